// Round 2
// baseline (1093.463 us; speedup 1.0000x reference)
//
#include <hip/hip_runtime.h>
#include <hip/hip_bf16.h>

typedef __attribute__((ext_vector_type(8))) short s16x8;
typedef __attribute__((ext_vector_type(4))) short s16x4;
typedef __attribute__((ext_vector_type(4))) float f32x4;

#define T_TOK 4096
#define DMODEL 2048
#define ISH 4096
#define IMOE 2048
#define NEXP 16
#define PADMAX 10240
#define MAXTILES 80

// ---- workspace layout (bytes) ----
#define XB_OFF   ((size_t)0)                          // ushort[T_TOK*DMODEL] = 16 MB
#define H_OFF    ((size_t)T_TOK*DMODEL*2)             // H: ushort, max(T*ISH, PADMAX*IMOE)
#define H_BYTES  ((size_t)PADMAX*IMOE*2)              // 41,943,040
#define Y_OFF    (H_OFF + H_BYTES)
#define Y_BYTES  ((size_t)2*T_TOK*DMODEL*4)           // 67 MB
#define C_OFF    (Y_OFF + Y_BYTES)
// control block offsets (bytes from C_OFF)
#define CNT_OFF    0
#define OFF_OFF    64
#define CUR_OFF    192
#define TILEE_OFF  256
#define TKI_OFF    1024
#define TKW_OFF    (TKI_OFF + T_TOK*2*4)
#define LCODE_OFF  (TKW_OFF + T_TOK*2*4)
#define LW_OFF     (LCODE_OFF + PADMAX*4)

__device__ __forceinline__ unsigned short f2bf(float f) {
    union { float f; unsigned u; } c; c.f = f;
    unsigned u = c.u;
    u += 0x7fffu + ((u >> 16) & 1u);   // RNE
    return (unsigned short)(u >> 16);
}

// 8 fp32 -> 8 bf16 via v_cvt_pk_bf16_f32 (compiler-generated)
__device__ __forceinline__ s16x8 cvt8(float4 a, float4 b) {
    union { __hip_bfloat162 h2[4]; s16x8 v; } u;
    u.h2[0] = __float22bfloat162_rn(make_float2(a.x, a.y));
    u.h2[1] = __float22bfloat162_rn(make_float2(a.z, a.w));
    u.h2[2] = __float22bfloat162_rn(make_float2(b.x, b.y));
    u.h2[3] = __float22bfloat162_rn(make_float2(b.z, b.w));
    return u.v;
}

// async global(16B per lane) -> LDS (linear, wave-uniform base + lane*16)
__device__ __forceinline__ void gl_lds16(const unsigned short* g, unsigned short* l) {
    __builtin_amdgcn_global_load_lds(
        (const __attribute__((address_space(1))) unsigned int*)g,
        (__attribute__((address_space(3))) unsigned int*)l,
        16, 0, 0);
}

// ---- cast x (fp32) -> xb (bf16) ----
__global__ void cvt_x_kernel(const float* __restrict__ x, unsigned short* __restrict__ xb) {
    size_t i = (size_t)blockIdx.x * 256 + threadIdx.x;   // 2,097,152 float4 chunks
    float4 v = ((const float4*)x)[i];
    s16x4 o;
    o[0] = (short)f2bf(v.x); o[1] = (short)f2bf(v.y);
    o[2] = (short)f2bf(v.z); o[3] = (short)f2bf(v.w);
    ((s16x4*)xb)[i] = o;
}

// ---- gate: fp64 logits, softmax top-2 renorm, counts ----
__global__ void gate_kernel(const float* __restrict__ x, const float* __restrict__ wg,
                            int* __restrict__ tki, float* __restrict__ tkw, int* __restrict__ cnt) {
    int t = blockIdx.x;
    __shared__ float xs[DMODEL];
    __shared__ float lg[NEXP];
    const float* xr = x + (size_t)t * DMODEL;
    for (int i = threadIdx.x; i < DMODEL; i += 256) xs[i] = xr[i];
    __syncthreads();
    int g = threadIdx.x >> 4, l = threadIdx.x & 15;
    const float* w = wg + (size_t)g * DMODEL;
    double s = 0.0;
    for (int i = l; i < DMODEL; i += 16) s += (double)xs[i] * (double)w[i];
    for (int m = 8; m >= 1; m >>= 1) s += __shfl_xor(s, m, 64);
    if (l == 0) lg[g] = (float)s;
    __syncthreads();
    if (threadIdx.x == 0) {
        float v0 = -1e30f, v1 = -1e30f; int i0 = 0, i1 = 0;
        for (int e = 0; e < NEXP; e++) {
            float v = lg[e];
            if (v > v0) { v1 = v0; i1 = i0; v0 = v; i0 = e; }
            else if (v > v1) { v1 = v; i1 = e; }
        }
        float w0 = 1.f / (1.f + expf(v1 - v0));
        float w1 = 1.f - w0;
        tki[t*2] = i0; tki[t*2+1] = i1;
        tkw[t*2] = w0; tkw[t*2+1] = w1;
        atomicAdd(&cnt[i0], 1); atomicAdd(&cnt[i1], 1);
    }
}

// ---- scan: 128-aligned offsets, tile->expert map, dummy fill ----
__global__ void scan_kernel(const int* __restrict__ cnt, int* __restrict__ off,
                            int* __restrict__ cur, int* __restrict__ tile_e,
                            int* __restrict__ lcode) {
    __shared__ int soff[17];
    if (threadIdx.x == 0) {
        int o = 0;
        for (int e = 0; e < NEXP; e++) {
            soff[e] = o; off[e] = o; cur[e] = 0;
            o += (cnt[e] + 127) & ~127;
        }
        soff[16] = o; off[16] = o;
    }
    __syncthreads();
    int ntiles = soff[16] >> 7;
    for (int i = threadIdx.x; i < MAXTILES; i += 256) {
        int e = -1;
        if (i < ntiles) {
            for (int j = 0; j < NEXP; j++)
                if (i*128 >= soff[j] && i*128 < soff[j+1]) e = j;
        }
        tile_e[i] = e;
    }
    for (int p = threadIdx.x; p < PADMAX; p += 256) lcode[p] = -1;
}

__global__ void fill_kernel(const int* __restrict__ tki, const float* __restrict__ tkw,
                            const int* __restrict__ off, int* __restrict__ cur,
                            int* __restrict__ lcode, float* __restrict__ lw) {
    int t = blockIdx.x * 256 + threadIdx.x;
    if (t >= T_TOK) return;
    for (int k = 0; k < 2; k++) {
        int e = tki[t*2+k];
        int p = atomicAdd(&cur[e], 1);
        int pos = off[e] + p;
        lcode[pos] = t*2 + k;
        lw[pos] = tkw[t*2+k];
    }
}

// ---- GEMM1: H = silu(A@W1^T) * (A@W3^T) * wt ----
// A via global_load_lds (bf16, gathered); B1/B3 fp32 -> cvt_pk bf16, T14 prefetch.
template<bool ROUTED>
__global__ __launch_bounds__(256, 2)
void gemm1_kernel(const unsigned short* __restrict__ xb,
                  const float* __restrict__ w1b, const float* __restrict__ w3b,
                  unsigned short* __restrict__ H, const int N,
                  const int* __restrict__ list_code, const float* __restrict__ list_w,
                  const int* __restrict__ tile_e) {
    const int K = DMODEL;
    // bijective XCD swizzle, column-major chunking (same-XCD blocks share B-panel)
    int nMT = gridDim.y;
    int wg0 = blockIdx.y * gridDim.x + blockIdx.x;
    int q8 = (gridDim.x * gridDim.y) >> 3;
    int s = (wg0 & 7) * q8 + (wg0 >> 3);
    int mt = s % nMT, nt = s / nMT;
    const float *w1 = w1b, *w3 = w3b;
    if (ROUTED) {
        int e = tile_e[mt];
        if (e < 0) return;
        size_t es = (size_t)N * K;
        w1 += (size_t)e * es; w3 += (size_t)e * es;
    }
    int m0 = mt*128, n0 = nt*128;
    __shared__ alignas(16) unsigned short As[128*32];
    __shared__ alignas(16) unsigned short B1s[128*32];
    __shared__ alignas(16) unsigned short B3s[128*32];
    __shared__ int   toks[128];
    __shared__ float wts[128];
    int tid = threadIdx.x;
    if (tid < 128) {
        if (ROUTED) {
            int code = list_code[m0 + tid];
            toks[tid] = (code < 0) ? 0 : (code >> 1);
            wts[tid]  = (code < 0) ? 0.f : list_w[m0 + tid];
        } else {
            toks[tid] = m0 + tid; wts[tid] = 1.f;
        }
    }
    __syncthreads();

    // per-thread staging geometry: chunk c = i*256+tid covers 16B; row=c>>2, q=c&3
    int ra = tid >> 2, qa = tid & 3;
    const unsigned short* asrc0 = xb + (size_t)toks[ra]      * K + qa*8;
    const unsigned short* asrc1 = xb + (size_t)toks[ra + 64] * K + qa*8;
    unsigned short* adst0 = &As[tid * 8];
    unsigned short* adst1 = &As[(256 + tid) * 8];
    const float* b1p0 = w1 + (size_t)(n0 + ra)      * K + qa*8;
    const float* b1p1 = w1 + (size_t)(n0 + ra + 64) * K + qa*8;
    const float* b3p0 = w3 + (size_t)(n0 + ra)      * K + qa*8;
    const float* b3p1 = w3 + (size_t)(n0 + ra + 64) * K + qa*8;
    unsigned short* b1d0 = &B1s[tid * 8];
    unsigned short* b1d1 = &B1s[(256 + tid) * 8];
    unsigned short* b3d0 = &B3s[tid * 8];
    unsigned short* b3d1 = &B3s[(256 + tid) * 8];

    f32x4 acc1[4][4], acc2[4][4];
    #pragma unroll
    for (int a = 0; a < 4; a++)
        #pragma unroll
        for (int b = 0; b < 4; b++) {
            acc1[a][b] = (f32x4){0.f,0.f,0.f,0.f};
            acc2[a][b] = (f32x4){0.f,0.f,0.f,0.f};
        }

    int wid = tid >> 6, lane = tid & 63;
    int wm = wid >> 1, wn = wid & 1;
    int ar = wm*64 + (lane & 15);
    int br = wn*64 + (lane & 15);
    int kk = (lane >> 4) * 8;

    // prefetch B for k0=0
    float4 r10a = *(const float4*)(b1p0);     float4 r10b = *(const float4*)(b1p0 + 4);
    float4 r11a = *(const float4*)(b1p1);     float4 r11b = *(const float4*)(b1p1 + 4);
    float4 r30a = *(const float4*)(b3p0);     float4 r30b = *(const float4*)(b3p0 + 4);
    float4 r31a = *(const float4*)(b3p1);     float4 r31b = *(const float4*)(b3p1 + 4);

    for (int k0 = 0; k0 < K; k0 += 32) {
        __syncthreads();                      // prev iter's LDS reads done
        *(s16x8*)b1d0 = cvt8(r10a, r10b);
        *(s16x8*)b1d1 = cvt8(r11a, r11b);
        *(s16x8*)b3d0 = cvt8(r30a, r30b);
        *(s16x8*)b3d1 = cvt8(r31a, r31b);
        gl_lds16(asrc0 + k0, adst0);
        gl_lds16(asrc1 + k0, adst1);
        __syncthreads();                      // drains gload_lds + ds_writes
        int kn = (k0 + 32 < K) ? (k0 + 32) : 0;   // T14: issue next loads over MFMA
        r10a = *(const float4*)(b1p0 + kn);   r10b = *(const float4*)(b1p0 + kn + 4);
        r11a = *(const float4*)(b1p1 + kn);   r11b = *(const float4*)(b1p1 + kn + 4);
        r30a = *(const float4*)(b3p0 + kn);   r30b = *(const float4*)(b3p0 + kn + 4);
        r31a = *(const float4*)(b3p1 + kn);   r31b = *(const float4*)(b3p1 + kn + 4);

        s16x8 a[4], b1f[4], b3f[4];
        #pragma unroll
        for (int f = 0; f < 4; f++) {
            a[f]   = *(const s16x8*)&As [(ar + f*16)*32 + kk];
            b1f[f] = *(const s16x8*)&B1s[(br + f*16)*32 + kk];
            b3f[f] = *(const s16x8*)&B3s[(br + f*16)*32 + kk];
        }
        #pragma unroll
        for (int mf = 0; mf < 4; mf++)
            #pragma unroll
            for (int nf = 0; nf < 4; nf++) {
                acc1[mf][nf] = __builtin_amdgcn_mfma_f32_16x16x32_bf16(a[mf], b1f[nf], acc1[mf][nf], 0,0,0);
                acc2[mf][nf] = __builtin_amdgcn_mfma_f32_16x16x32_bf16(a[mf], b3f[nf], acc2[mf][nf], 0,0,0);
            }
    }
    // epilogue: silu(acc1)*acc2*wt -> bf16 H
    #pragma unroll
    for (int mf = 0; mf < 4; mf++) {
        int ib = wm*64 + mf*16 + (lane >> 4)*4;
        #pragma unroll
        for (int nf = 0; nf < 4; nf++) {
            int j = n0 + wn*64 + nf*16 + (lane & 15);
            #pragma unroll
            for (int r = 0; r < 4; r++) {
                int i = ib + r;
                float v1 = acc1[mf][nf][r], v2 = acc2[mf][nf][r];
                float sg = v1 / (1.f + __expf(-v1));
                float h = sg * v2 * wts[i];
                H[(size_t)(m0+i)*N + j] = f2bf(h);
            }
        }
    }
}

// ---- GEMM2: Y = H @ W2^T ----
template<bool ROUTED>
__global__ __launch_bounds__(256, 2)
void gemm2_kernel(const unsigned short* __restrict__ Hm, const float* __restrict__ w2b,
                  float* __restrict__ out, float* __restrict__ y, const int K,
                  const int* __restrict__ list_code, const int* __restrict__ tile_e) {
    const int N = DMODEL;
    int nMT = gridDim.y;
    int wg0 = blockIdx.y * gridDim.x + blockIdx.x;
    int q8 = (gridDim.x * gridDim.y) >> 3;
    int s = (wg0 & 7) * q8 + (wg0 >> 3);
    int mt = s % nMT, nt = s / nMT;
    const float* w2 = w2b;
    if (ROUTED) {
        int e = tile_e[mt];
        if (e < 0) return;
        w2 += (size_t)e * N * K;
    }
    int m0 = mt*128, n0 = nt*128;
    __shared__ alignas(16) unsigned short As[128*32];
    __shared__ alignas(16) unsigned short Bs[128*32];
    __shared__ int codes[128];
    int tid = threadIdx.x;
    if (ROUTED && tid < 128) codes[tid] = list_code[m0 + tid];

    int ra = tid >> 2, qa = tid & 3;
    const unsigned short* asrc0 = Hm + (size_t)(m0 + ra)      * K + qa*8;
    const unsigned short* asrc1 = Hm + (size_t)(m0 + ra + 64) * K + qa*8;
    unsigned short* adst0 = &As[tid * 8];
    unsigned short* adst1 = &As[(256 + tid) * 8];
    const float* bp0 = w2 + (size_t)(n0 + ra)      * K + qa*8;
    const float* bp1 = w2 + (size_t)(n0 + ra + 64) * K + qa*8;
    unsigned short* bd0 = &Bs[tid * 8];
    unsigned short* bd1 = &Bs[(256 + tid) * 8];

    f32x4 acc[4][4];
    #pragma unroll
    for (int a = 0; a < 4; a++)
        #pragma unroll
        for (int b = 0; b < 4; b++) acc[a][b] = (f32x4){0.f,0.f,0.f,0.f};

    int wid = tid >> 6, lane = tid & 63;
    int wm = wid >> 1, wn = wid & 1;
    int ar = wm*64 + (lane & 15);
    int br = wn*64 + (lane & 15);
    int kk = (lane >> 4) * 8;

    float4 r0a = *(const float4*)(bp0);  float4 r0b = *(const float4*)(bp0 + 4);
    float4 r1a = *(const float4*)(bp1);  float4 r1b = *(const float4*)(bp1 + 4);

    for (int k0 = 0; k0 < K; k0 += 32) {
        __syncthreads();
        *(s16x8*)bd0 = cvt8(r0a, r0b);
        *(s16x8*)bd1 = cvt8(r1a, r1b);
        gl_lds16(asrc0 + k0, adst0);
        gl_lds16(asrc1 + k0, adst1);
        __syncthreads();
        int kn = (k0 + 32 < K) ? (k0 + 32) : 0;
        r0a = *(const float4*)(bp0 + kn);  r0b = *(const float4*)(bp0 + kn + 4);
        r1a = *(const float4*)(bp1 + kn);  r1b = *(const float4*)(bp1 + kn + 4);

        s16x8 a[4], b[4];
        #pragma unroll
        for (int f = 0; f < 4; f++) {
            a[f] = *(const s16x8*)&As[(ar + f*16)*32 + kk];
            b[f] = *(const s16x8*)&Bs[(br + f*16)*32 + kk];
        }
        #pragma unroll
        for (int mf = 0; mf < 4; mf++)
            #pragma unroll
            for (int nf = 0; nf < 4; nf++)
                acc[mf][nf] = __builtin_amdgcn_mfma_f32_16x16x32_bf16(a[mf], b[nf], acc[mf][nf], 0,0,0);
    }
    #pragma unroll
    for (int mf = 0; mf < 4; mf++) {
        int ib = wm*64 + mf*16 + (lane >> 4)*4;
        #pragma unroll
        for (int nf = 0; nf < 4; nf++) {
            int j = n0 + wn*64 + nf*16 + (lane & 15);
            #pragma unroll
            for (int r = 0; r < 4; r++) {
                int i = ib + r;
                float v = acc[mf][nf][r];
                if (!ROUTED) {
                    out[(size_t)(m0+i)*N + j] = v;
                } else {
                    int code = codes[i];
                    if (code >= 0)
                        y[((size_t)(code & 1)*T_TOK + (code >> 1))*N + j] = v;
                }
            }
        }
    }
}

// ---- combine: out += y0 + y1 ----
__global__ void combine_kernel(float* __restrict__ out, const float* __restrict__ y) {
    size_t i = (size_t)blockIdx.x * 256 + threadIdx.x;   // float4 index
    float4 o = ((const float4*)out)[i];
    float4 a = ((const float4*)y)[i];
    float4 b = ((const float4*)(y + (size_t)T_TOK*DMODEL))[i];
    o.x += a.x + b.x; o.y += a.y + b.y; o.z += a.z + b.z; o.w += a.w + b.w;
    ((float4*)out)[i] = o;
}

extern "C" void kernel_launch(void* const* d_in, const int* in_sizes, int n_in,
                              void* d_out, int out_size, void* d_ws, size_t ws_size,
                              hipStream_t stream) {
    const float* x   = (const float*)d_in[0];
    const float* wg  = (const float*)d_in[1];
    const float* sw1 = (const float*)d_in[2];
    const float* sw3 = (const float*)d_in[3];
    const float* sw2 = (const float*)d_in[4];
    const float* ew1 = (const float*)d_in[5];
    const float* ew3 = (const float*)d_in[6];
    const float* ew2 = (const float*)d_in[7];
    float* out = (float*)d_out;
    char* ws = (char*)d_ws;
    unsigned short* xb = (unsigned short*)(ws + XB_OFF);
    unsigned short* H  = (unsigned short*)(ws + H_OFF);
    float* y = (float*)(ws + Y_OFF);
    char* c = ws + C_OFF;
    int*   cnt    = (int*)  (c + CNT_OFF);
    int*   off    = (int*)  (c + OFF_OFF);
    int*   cur    = (int*)  (c + CUR_OFF);
    int*   tile_e = (int*)  (c + TILEE_OFF);
    int*   tki    = (int*)  (c + TKI_OFF);
    float* tkw    = (float*)(c + TKW_OFF);
    int*   lcode  = (int*)  (c + LCODE_OFF);
    float* lw     = (float*)(c + LW_OFF);

    hipMemsetAsync(cnt, 0, 64, stream);
    cvt_x_kernel<<<8192, 256, 0, stream>>>(x, xb);
    gate_kernel<<<T_TOK, 256, 0, stream>>>(x, wg, tki, tkw, cnt);
    scan_kernel<<<1, 256, 0, stream>>>(cnt, off, cur, tile_e, lcode);
    fill_kernel<<<16, 256, 0, stream>>>(tki, tkw, off, cur, lcode, lw);
    // shared expert
    gemm1_kernel<false><<<dim3(ISH/128, T_TOK/128), 256, 0, stream>>>(
        xb, sw1, sw3, H, ISH, nullptr, nullptr, nullptr);
    gemm2_kernel<false><<<dim3(DMODEL/128, T_TOK/128), 256, 0, stream>>>(
        H, sw2, out, nullptr, ISH, nullptr, nullptr);
    // routed experts (gathered, 128-aligned segments)
    gemm1_kernel<true><<<dim3(IMOE/128, MAXTILES), 256, 0, stream>>>(
        xb, ew1, ew3, H, IMOE, lcode, lw, tile_e);
    gemm2_kernel<true><<<dim3(DMODEL/128, MAXTILES), 256, 0, stream>>>(
        H, ew2, nullptr, y, IMOE, lcode, tile_e);
    combine_kernel<<<8192, 256, 0, stream>>>(out, y);
}

// Round 3
// 1026.735 us; speedup vs baseline: 1.0650x; 1.0650x over previous
//
#include <hip/hip_runtime.h>
#include <hip/hip_bf16.h>

typedef __attribute__((ext_vector_type(8))) short s16x8;
typedef __attribute__((ext_vector_type(4))) short s16x4;
typedef __attribute__((ext_vector_type(4))) float f32x4;

#define T_TOK 4096
#define DMODEL 2048
#define ISH 4096
#define IMOE 2048
#define NEXP 16
#define MAXTILES 48
#define PADMAX (MAXTILES*256)    // 12288

// ---- workspace layout (bytes) ----
#define XB_OFF   ((size_t)0)                          // ushort[T_TOK*DMODEL] = 16.8 MB
#define H_OFF    ((size_t)T_TOK*DMODEL*2)
#define H_BYTES  ((size_t)PADMAX*IMOE*2)              // 50.3 MB (covers T*ISH = 33.5 MB too)
#define Y_OFF    (H_OFF + H_BYTES)
#define Y_BYTES  ((size_t)2*T_TOK*DMODEL*2)           // bf16 routed outputs, 33.5 MB
#define C_OFF    (Y_OFF + Y_BYTES)
// control block offsets (bytes from C_OFF)
#define CNT_OFF    0
#define OFF_OFF    64
#define CUR_OFF    192
#define TILEE_OFF  256
#define TKI_OFF    1024
#define TKW_OFF    (TKI_OFF + T_TOK*2*4)
#define LCODE_OFF  (TKW_OFF + T_TOK*2*4)
#define LW_OFF     (LCODE_OFF + PADMAX*4)

__device__ __forceinline__ unsigned short f2bf(float f) {
    union { float f; unsigned u; } c; c.f = f;
    unsigned u = c.u;
    u += 0x7fffu + ((u >> 16) & 1u);   // RNE
    return (unsigned short)(u >> 16);
}
__device__ __forceinline__ float bf2f(unsigned short h) {
    union { unsigned u; float f; } c; c.u = ((unsigned)h) << 16; return c.f;
}

// 8 fp32 -> 8 bf16 via v_cvt_pk_bf16_f32
__device__ __forceinline__ s16x8 cvt8(float4 a, float4 b) {
    union { __hip_bfloat162 h2[4]; s16x8 v; } u;
    u.h2[0] = __float22bfloat162_rn(make_float2(a.x, a.y));
    u.h2[1] = __float22bfloat162_rn(make_float2(a.z, a.w));
    u.h2[2] = __float22bfloat162_rn(make_float2(b.x, b.y));
    u.h2[3] = __float22bfloat162_rn(make_float2(b.z, b.w));
    return u.v;
}

__device__ __forceinline__ void gl_lds16(const unsigned short* g, unsigned short* l) {
    __builtin_amdgcn_global_load_lds(
        (const __attribute__((address_space(1))) unsigned int*)g,
        (__attribute__((address_space(3))) unsigned int*)l,
        16, 0, 0);
}

// ---- cast x (fp32) -> xb (bf16) ----
__global__ void cvt_x_kernel(const float* __restrict__ x, unsigned short* __restrict__ xb) {
    size_t i = (size_t)blockIdx.x * 256 + threadIdx.x;
    float4 v = ((const float4*)x)[i];
    s16x4 o;
    o[0] = (short)f2bf(v.x); o[1] = (short)f2bf(v.y);
    o[2] = (short)f2bf(v.z); o[3] = (short)f2bf(v.w);
    ((s16x4*)xb)[i] = o;
}

// ---- gate: fp64 logits, softmax top-2 renorm, counts ----
__global__ void gate_kernel(const float* __restrict__ x, const float* __restrict__ wg,
                            int* __restrict__ tki, float* __restrict__ tkw, int* __restrict__ cnt) {
    int t = blockIdx.x;
    __shared__ float xs[DMODEL];
    __shared__ float lg[NEXP];
    const float* xr = x + (size_t)t * DMODEL;
    for (int i = threadIdx.x; i < DMODEL; i += 256) xs[i] = xr[i];
    __syncthreads();
    int g = threadIdx.x >> 4, l = threadIdx.x & 15;
    const float* w = wg + (size_t)g * DMODEL;
    double s = 0.0;
    for (int i = l; i < DMODEL; i += 16) s += (double)xs[i] * (double)w[i];
    for (int m = 8; m >= 1; m >>= 1) s += __shfl_xor(s, m, 64);
    if (l == 0) lg[g] = (float)s;
    __syncthreads();
    if (threadIdx.x == 0) {
        float v0 = -1e30f, v1 = -1e30f; int i0 = 0, i1 = 0;
        for (int e = 0; e < NEXP; e++) {
            float v = lg[e];
            if (v > v0) { v1 = v0; i1 = i0; v0 = v; i0 = e; }
            else if (v > v1) { v1 = v; i1 = e; }
        }
        float w0 = 1.f / (1.f + expf(v1 - v0));
        float w1 = 1.f - w0;
        tki[t*2] = i0; tki[t*2+1] = i1;
        tkw[t*2] = w0; tkw[t*2+1] = w1;
        atomicAdd(&cnt[i0], 1); atomicAdd(&cnt[i1], 1);
    }
}

// ---- scan: 256-aligned offsets, tile->expert map ----
__global__ void scan_kernel(const int* __restrict__ cnt, int* __restrict__ off,
                            int* __restrict__ cur, int* __restrict__ tile_e,
                            int* __restrict__ lcode) {
    __shared__ int soff[17];
    if (threadIdx.x == 0) {
        int o = 0;
        for (int e = 0; e < NEXP; e++) {
            soff[e] = o; off[e] = o; cur[e] = 0;
            o += (cnt[e] + 255) & ~255;
        }
        soff[16] = o; off[16] = o;
    }
    __syncthreads();
    int ntiles = soff[16] >> 8;
    for (int i = threadIdx.x; i < MAXTILES; i += 256) {
        int e = -1;
        if (i < ntiles) {
            for (int j = 0; j < NEXP; j++)
                if (i*256 >= soff[j] && i*256 < soff[j+1]) e = j;
        }
        tile_e[i] = e;
    }
    for (int p = threadIdx.x; p < PADMAX; p += 256) lcode[p] = -1;
}

__global__ void fill_kernel(const int* __restrict__ tki, const float* __restrict__ tkw,
                            const int* __restrict__ off, int* __restrict__ cur,
                            int* __restrict__ lcode, float* __restrict__ lw) {
    int t = blockIdx.x * 256 + threadIdx.x;
    if (t >= T_TOK) return;
    for (int k = 0; k < 2; k++) {
        int e = tki[t*2+k];
        int p = atomicAdd(&cur[e], 1);
        int pos = off[e] + p;
        lcode[pos] = t*2 + k;
        lw[pos] = tkw[t*2+k];
    }
}

// ===================================================================
// Pipelined GEMM structure: BM=256 BN=128 BK=64, 8 waves (4M x 2N),
// wave tile 64x64, LDS double-buffered, one barrier per K-step.
// LDS tiles XOR-swizzled: byte ^= ((row&7)<<4) within each 128B row.
// A staged via global_load_lds (linear dest, inverse-swizzled source);
// B (fp32) reg-staged: loads issued before MFMA phase, cvt+ds_write after.
// ===================================================================

// ---- GEMM1: H = silu(A@W1^T) * (A@W3^T) * wt ----
template<bool ROUTED>
__global__ __launch_bounds__(512, 2)
void gemm1_kernel(const unsigned short* __restrict__ xb,
                  const float* __restrict__ w1b, const float* __restrict__ w3b,
                  unsigned short* __restrict__ H, const int N,
                  const int* __restrict__ list_code, const float* __restrict__ list_w,
                  const int* __restrict__ tile_e) {
    const int K = DMODEL;
    const int NT = K / 64;
    // bijective XCD swizzle (nwg % 8 == 0), mt fastest within an XCD chunk
    int gx = gridDim.x, gy = gridDim.y;
    int wg0 = blockIdx.y * gx + blockIdx.x;
    int cpx = (gx * gy) >> 3;
    int sw = (wg0 & 7) * cpx + (wg0 >> 3);
    int mt = sw % gy, nt = sw / gy;
    const float *w1 = w1b, *w3 = w3b;
    if (ROUTED) {
        int e = tile_e[mt];
        if (e < 0) return;
        size_t es = (size_t)N * K;
        w1 += (size_t)e * es; w3 += (size_t)e * es;
    }
    int m0 = mt*256, n0 = nt*128;

    __shared__ alignas(16) unsigned short Ab [2][256*64];  // 64 KB
    __shared__ alignas(16) unsigned short B1b[2][128*64];  // 32 KB
    __shared__ alignas(16) unsigned short B3b[2][128*64];  // 32 KB
    __shared__ int   toks[256];
    __shared__ float wts[256];

    int tid = threadIdx.x;
    if (tid < 256) {
        if (ROUTED) {
            int code = list_code[m0 + tid];
            toks[tid] = (code < 0) ? 0 : (code >> 1);
            wts[tid]  = (code < 0) ? 0.f : list_w[m0 + tid];
        } else {
            toks[tid] = m0 + tid; wts[tid] = 1.f;
        }
    }
    __syncthreads();

    // ---- A staging geometry: 4 x gl_lds16, chunk c = r*512+tid ----
    const unsigned short* aSrc[4];
    int aDst[4];
    #pragma unroll
    for (int r = 0; r < 4; r++) {
        int c = r*512 + tid, row = c >> 3;
        int kb = ((c & 7) * 16) ^ ((row & 7) << 4);   // inverse-swizzled source col (bytes)
        aSrc[r] = xb + (size_t)toks[row] * K + (kb >> 1);
        aDst[r] = c * 8;                               // linear dest (ushort elems)
    }
    // ---- B staging geometry: pairs p0=tid, p1=tid+512 per matrix ----
    int p0 = tid, p1 = tid + 512;
    int r0 = p0 >> 3, r1 = p1 >> 3;
    const float* b1s0 = w1 + (size_t)(n0 + r0) * K + (p0 & 7) * 8;
    const float* b1s1 = w1 + (size_t)(n0 + r1) * K + (p1 & 7) * 8;
    const float* b3s0 = w3 + (size_t)(n0 + r0) * K + (p0 & 7) * 8;
    const float* b3s1 = w3 + (size_t)(n0 + r1) * K + (p1 & 7) * 8;
    int bD0 = r0*64 + ((((p0 & 7) ^ (r0 & 7)) << 3));  // swizzled dest (ushort elems)
    int bD1 = r1*64 + ((((p1 & 7) ^ (r1 & 7)) << 3));

    // ---- wave / fragment geometry ----
    int wid = tid >> 6, lane = tid & 63;
    int wr = wid >> 1, wc = wid & 1;
    int l15 = lane & 15, lq = lane >> 4, lx = (lane & 7) << 4;
    int arow = wr*64 + l15, brow = wc*64 + l15;
    int ka0 = (((0*64) + lq*16) ^ lx) >> 1;            // swizzled k-offsets (ushort elems)
    int ka1 = (((1*64) + lq*16) ^ lx) >> 1;

    f32x4 acc1[4][4], acc2[4][4];
    #pragma unroll
    for (int a = 0; a < 4; a++)
        #pragma unroll
        for (int b = 0; b < 4; b++) {
            acc1[a][b] = (f32x4){0.f,0.f,0.f,0.f};
            acc2[a][b] = (f32x4){0.f,0.f,0.f,0.f};
        }

    // ---- prologue: fill buf 0 for k0 = 0 ----
    {
        float4 v10a = *(const float4*)(b1s0);     float4 v10b = *(const float4*)(b1s0 + 4);
        float4 v11a = *(const float4*)(b1s1);     float4 v11b = *(const float4*)(b1s1 + 4);
        float4 v30a = *(const float4*)(b3s0);     float4 v30b = *(const float4*)(b3s0 + 4);
        float4 v31a = *(const float4*)(b3s1);     float4 v31b = *(const float4*)(b3s1 + 4);
        #pragma unroll
        for (int r = 0; r < 4; r++) gl_lds16(aSrc[r], &Ab[0][aDst[r]]);
        *(s16x8*)&B1b[0][bD0] = cvt8(v10a, v10b);
        *(s16x8*)&B1b[0][bD1] = cvt8(v11a, v11b);
        *(s16x8*)&B3b[0][bD0] = cvt8(v30a, v30b);
        *(s16x8*)&B3b[0][bD1] = cvt8(v31a, v31b);
    }
    __syncthreads();

    int cur = 0;
    for (int t = 0; t < NT; ++t) {
        bool pre = (t + 1 < NT);
        int kn = (t + 1) * 64;
        float4 v10a, v10b, v11a, v11b, v30a, v30b, v31a, v31b;
        if (pre) {
            // issue B loads for t+1 (results consumed after compute)
            v10a = *(const float4*)(b1s0 + kn);  v10b = *(const float4*)(b1s0 + kn + 4);
            v11a = *(const float4*)(b1s1 + kn);  v11b = *(const float4*)(b1s1 + kn + 4);
            v30a = *(const float4*)(b3s0 + kn);  v30b = *(const float4*)(b3s0 + kn + 4);
            v31a = *(const float4*)(b3s1 + kn);  v31b = *(const float4*)(b3s1 + kn + 4);
            // issue A global->LDS for t+1 into the other buffer
            #pragma unroll
            for (int r = 0; r < 4; r++) gl_lds16(aSrc[r] + kn, &Ab[cur ^ 1][aDst[r]]);
        }
        __builtin_amdgcn_sched_barrier(0);
        // ---- compute from buf[cur] ----
        const unsigned short* Ac  = &Ab [cur][0];
        const unsigned short* B1c = &B1b[cur][0];
        const unsigned short* B3c = &B3b[cur][0];
        #pragma unroll
        for (int s = 0; s < 2; s++) {
            int ka = s ? ka1 : ka0;
            s16x8 af[4], b1f[4], b3f[4];
            #pragma unroll
            for (int f = 0; f < 4; f++) {
                af[f]  = *(const s16x8*)&Ac [(arow + f*16)*64 + ka];
                b1f[f] = *(const s16x8*)&B1c[(brow + f*16)*64 + ka];
                b3f[f] = *(const s16x8*)&B3c[(brow + f*16)*64 + ka];
            }
            __builtin_amdgcn_s_setprio(1);
            #pragma unroll
            for (int mf = 0; mf < 4; mf++)
                #pragma unroll
                for (int nf = 0; nf < 4; nf++) {
                    acc1[mf][nf] = __builtin_amdgcn_mfma_f32_16x16x32_bf16(af[mf], b1f[nf], acc1[mf][nf], 0,0,0);
                    acc2[mf][nf] = __builtin_amdgcn_mfma_f32_16x16x32_bf16(af[mf], b3f[nf], acc2[mf][nf], 0,0,0);
                }
            __builtin_amdgcn_s_setprio(0);
        }
        __builtin_amdgcn_sched_barrier(0);
        if (pre) {
            *(s16x8*)&B1b[cur ^ 1][bD0] = cvt8(v10a, v10b);
            *(s16x8*)&B1b[cur ^ 1][bD1] = cvt8(v11a, v11b);
            *(s16x8*)&B3b[cur ^ 1][bD0] = cvt8(v30a, v30b);
            *(s16x8*)&B3b[cur ^ 1][bD1] = cvt8(v31a, v31b);
        }
        __syncthreads();   // drains ds_writes (lgkm) + A gl_lds (vmcnt0) for t+1
        cur ^= 1;
    }

    // ---- epilogue: silu(acc1)*acc2*wt -> bf16 H ----
    #pragma unroll
    for (int mf = 0; mf < 4; mf++) {
        int ib = wr*64 + mf*16 + lq*4;
        #pragma unroll
        for (int nf = 0; nf < 4; nf++) {
            int j = n0 + wc*64 + nf*16 + l15;
            #pragma unroll
            for (int r = 0; r < 4; r++) {
                int i = ib + r;
                float v1 = acc1[mf][nf][r], v2 = acc2[mf][nf][r];
                float sg = v1 / (1.f + __expf(-v1));
                float h = sg * v2 * wts[i];
                H[(size_t)(m0+i)*N + j] = f2bf(h);
            }
        }
    }
}

// ---- GEMM2: Y = H @ W2^T ----
template<bool ROUTED>
__global__ __launch_bounds__(512, 2)
void gemm2_kernel(const unsigned short* __restrict__ Hm, const float* __restrict__ w2b,
                  float* __restrict__ out, unsigned short* __restrict__ y, const int K,
                  const int* __restrict__ list_code, const int* __restrict__ tile_e) {
    const int N = DMODEL;
    const int NT = K / 64;
    int gx = gridDim.x, gy = gridDim.y;
    int wg0 = blockIdx.y * gx + blockIdx.x;
    int cpx = (gx * gy) >> 3;
    int sw = (wg0 & 7) * cpx + (wg0 >> 3);
    int mt = sw % gy, nt = sw / gy;
    const float* w2 = w2b;
    if (ROUTED) {
        int e = tile_e[mt];
        if (e < 0) return;
        w2 += (size_t)e * N * K;
    }
    int m0 = mt*256, n0 = nt*128;

    __shared__ alignas(16) unsigned short Ab[2][256*64];  // 64 KB
    __shared__ alignas(16) unsigned short Bb[2][128*64];  // 32 KB
    __shared__ int codes[256];
    int tid = threadIdx.x;
    if (ROUTED && tid < 256) codes[tid] = list_code[m0 + tid];
    if (ROUTED) __syncthreads();

    const unsigned short* aSrc[4];
    int aDst[4];
    #pragma unroll
    for (int r = 0; r < 4; r++) {
        int c = r*512 + tid, row = c >> 3;
        int kb = ((c & 7) * 16) ^ ((row & 7) << 4);
        aSrc[r] = Hm + (size_t)(m0 + row) * K + (kb >> 1);
        aDst[r] = c * 8;
    }
    int p0 = tid, p1 = tid + 512;
    int r0 = p0 >> 3, r1 = p1 >> 3;
    const float* bs0 = w2 + (size_t)(n0 + r0) * K + (p0 & 7) * 8;
    const float* bs1 = w2 + (size_t)(n0 + r1) * K + (p1 & 7) * 8;
    int bD0 = r0*64 + ((((p0 & 7) ^ (r0 & 7)) << 3));
    int bD1 = r1*64 + ((((p1 & 7) ^ (r1 & 7)) << 3));

    int wid = tid >> 6, lane = tid & 63;
    int wr = wid >> 1, wc = wid & 1;
    int l15 = lane & 15, lq = lane >> 4, lx = (lane & 7) << 4;
    int arow = wr*64 + l15, brow = wc*64 + l15;
    int ka0 = (((0*64) + lq*16) ^ lx) >> 1;
    int ka1 = (((1*64) + lq*16) ^ lx) >> 1;

    f32x4 acc[4][4];
    #pragma unroll
    for (int a = 0; a < 4; a++)
        #pragma unroll
        for (int b = 0; b < 4; b++) acc[a][b] = (f32x4){0.f,0.f,0.f,0.f};

    {
        float4 v0a = *(const float4*)(bs0);  float4 v0b = *(const float4*)(bs0 + 4);
        float4 v1a = *(const float4*)(bs1);  float4 v1b = *(const float4*)(bs1 + 4);
        #pragma unroll
        for (int r = 0; r < 4; r++) gl_lds16(aSrc[r], &Ab[0][aDst[r]]);
        *(s16x8*)&Bb[0][bD0] = cvt8(v0a, v0b);
        *(s16x8*)&Bb[0][bD1] = cvt8(v1a, v1b);
    }
    __syncthreads();

    int cur = 0;
    for (int t = 0; t < NT; ++t) {
        bool pre = (t + 1 < NT);
        int kn = (t + 1) * 64;
        float4 v0a, v0b, v1a, v1b;
        if (pre) {
            v0a = *(const float4*)(bs0 + kn);  v0b = *(const float4*)(bs0 + kn + 4);
            v1a = *(const float4*)(bs1 + kn);  v1b = *(const float4*)(bs1 + kn + 4);
            #pragma unroll
            for (int r = 0; r < 4; r++) gl_lds16(aSrc[r] + kn, &Ab[cur ^ 1][aDst[r]]);
        }
        __builtin_amdgcn_sched_barrier(0);
        const unsigned short* Ac = &Ab[cur][0];
        const unsigned short* Bc = &Bb[cur][0];
        #pragma unroll
        for (int s = 0; s < 2; s++) {
            int ka = s ? ka1 : ka0;
            s16x8 af[4], bf[4];
            #pragma unroll
            for (int f = 0; f < 4; f++) {
                af[f] = *(const s16x8*)&Ac[(arow + f*16)*64 + ka];
                bf[f] = *(const s16x8*)&Bc[(brow + f*16)*64 + ka];
            }
            __builtin_amdgcn_s_setprio(1);
            #pragma unroll
            for (int mf = 0; mf < 4; mf++)
                #pragma unroll
                for (int nf = 0; nf < 4; nf++)
                    acc[mf][nf] = __builtin_amdgcn_mfma_f32_16x16x32_bf16(af[mf], bf[nf], acc[mf][nf], 0,0,0);
            __builtin_amdgcn_s_setprio(0);
        }
        __builtin_amdgcn_sched_barrier(0);
        if (pre) {
            *(s16x8*)&Bb[cur ^ 1][bD0] = cvt8(v0a, v0b);
            *(s16x8*)&Bb[cur ^ 1][bD1] = cvt8(v1a, v1b);
        }
        __syncthreads();
        cur ^= 1;
    }

    #pragma unroll
    for (int mf = 0; mf < 4; mf++) {
        int ib = wr*64 + mf*16 + lq*4;
        #pragma unroll
        for (int nf = 0; nf < 4; nf++) {
            int j = n0 + wc*64 + nf*16 + l15;
            #pragma unroll
            for (int r = 0; r < 4; r++) {
                int i = ib + r;
                float v = acc[mf][nf][r];
                if (!ROUTED) {
                    out[(size_t)(m0+i)*N + j] = v;
                } else {
                    int code = codes[i];
                    if (code >= 0)
                        y[((size_t)(code & 1)*T_TOK + (code >> 1))*N + j] = f2bf(v);
                }
            }
        }
    }
}

// ---- combine: out += y0 + y1 (y bf16) ----
__global__ void combine_kernel(float* __restrict__ out, const unsigned short* __restrict__ y) {
    size_t i = (size_t)blockIdx.x * 256 + threadIdx.x;   // index of 8-elem group
    s16x8 a = ((const s16x8*)y)[i];
    s16x8 b = ((const s16x8*)(y + (size_t)T_TOK*DMODEL))[i];
    float4 o0 = ((const float4*)out)[i*2];
    float4 o1 = ((const float4*)out)[i*2+1];
    o0.x += bf2f((unsigned short)a[0]) + bf2f((unsigned short)b[0]);
    o0.y += bf2f((unsigned short)a[1]) + bf2f((unsigned short)b[1]);
    o0.z += bf2f((unsigned short)a[2]) + bf2f((unsigned short)b[2]);
    o0.w += bf2f((unsigned short)a[3]) + bf2f((unsigned short)b[3]);
    o1.x += bf2f((unsigned short)a[4]) + bf2f((unsigned short)b[4]);
    o1.y += bf2f((unsigned short)a[5]) + bf2f((unsigned short)b[5]);
    o1.z += bf2f((unsigned short)a[6]) + bf2f((unsigned short)b[6]);
    o1.w += bf2f((unsigned short)a[7]) + bf2f((unsigned short)b[7]);
    ((float4*)out)[i*2]   = o0;
    ((float4*)out)[i*2+1] = o1;
}

extern "C" void kernel_launch(void* const* d_in, const int* in_sizes, int n_in,
                              void* d_out, int out_size, void* d_ws, size_t ws_size,
                              hipStream_t stream) {
    const float* x   = (const float*)d_in[0];
    const float* wg  = (const float*)d_in[1];
    const float* sw1 = (const float*)d_in[2];
    const float* sw3 = (const float*)d_in[3];
    const float* sw2 = (const float*)d_in[4];
    const float* ew1 = (const float*)d_in[5];
    const float* ew3 = (const float*)d_in[6];
    const float* ew2 = (const float*)d_in[7];
    float* out = (float*)d_out;
    char* ws = (char*)d_ws;
    unsigned short* xb = (unsigned short*)(ws + XB_OFF);
    unsigned short* H  = (unsigned short*)(ws + H_OFF);
    unsigned short* y  = (unsigned short*)(ws + Y_OFF);
    char* c = ws + C_OFF;
    int*   cnt    = (int*)  (c + CNT_OFF);
    int*   off    = (int*)  (c + OFF_OFF);
    int*   cur    = (int*)  (c + CUR_OFF);
    int*   tile_e = (int*)  (c + TILEE_OFF);
    int*   tki    = (int*)  (c + TKI_OFF);
    float* tkw    = (float*)(c + TKW_OFF);
    int*   lcode  = (int*)  (c + LCODE_OFF);
    float* lw     = (float*)(c + LW_OFF);

    hipMemsetAsync(cnt, 0, 64, stream);
    cvt_x_kernel<<<8192, 256, 0, stream>>>(x, xb);
    gate_kernel<<<T_TOK, 256, 0, stream>>>(x, wg, tki, tkw, cnt);
    scan_kernel<<<1, 256, 0, stream>>>(cnt, off, cur, tile_e, lcode);
    fill_kernel<<<16, 256, 0, stream>>>(tki, tkw, off, cur, lcode, lw);
    // shared expert: gemm1 grid (N/128, M/256) = (32,16); gemm2 (16,16)
    gemm1_kernel<false><<<dim3(ISH/128, T_TOK/256), 512, 0, stream>>>(
        xb, sw1, sw3, H, ISH, nullptr, nullptr, nullptr);
    gemm2_kernel<false><<<dim3(DMODEL/128, T_TOK/256), 512, 0, stream>>>(
        H, sw2, out, nullptr, ISH, nullptr, nullptr);
    // routed experts (gathered, 256-aligned segments): grids (16,48)
    gemm1_kernel<true><<<dim3(IMOE/128, MAXTILES), 512, 0, stream>>>(
        xb, ew1, ew3, H, IMOE, lcode, lw, tile_e);
    gemm2_kernel<true><<<dim3(DMODEL/128, MAXTILES), 512, 0, stream>>>(
        H, ew2, nullptr, y, IMOE, lcode, tile_e);
    combine_kernel<<<4096, 256, 0, stream>>>(out, y);
}